// Round 7
// baseline (10419.935 us; speedup 1.0000x reference)
//
#include <hip/hip_runtime.h>

#define B64 64
#define SE 512
#define HD 1024
#define ED 512
#define NV 10000
#define TT 20
#define MM 1536
#define MASK_VALF -10000000.0f

// ---- workspace offsets (floats) ----
#define OFF_XT    0                    // inpT [512][64]
#define OFF_HA    32768                // hA [1024][64]
#define OFF_HB    98304                // hB [1024][64]
#define OFF_CT    163840               // cT [1024][64]
#define OFF_A     229376               // REGION A: GPART[6][4096][64] | H1P[12][1536][64] | LP[6][10000][64]
#define OFF_QP    4069376              // qpart [8][1024][64]
#define OFF_QF    4593664              // qf [64][1024]
#define OFF_FM    4659200              // [1024]
#define OFF_FL    4660224              // [1024]
#define OFF_FACC  4661248              // [1024][1024]
#define OFF_XT2   5709824              // [1536][64]
#define OFF_H1T   5808128              // [1536][64]
#define OFF_ARGV  5906432              // [1250][64]
#define OFF_ARGI  5986432              // [1250][64] (int)
#define OFF_MASKT 6066432              // [10000][64]
#define OFF_BUF   6706432              // [64][20][512]
#define OFF_BUFT  7361792              // [512][20][64]
#define OFF_KVP   8017152              // [64][20][64]
#define OFF_CNT   8099072              // [521] int counters (gates 128 | q 32 | h1 48 | glog 313)
// end: ~8099600 floats ~= 32.4 MB

#define CNT_GATES 0
#define CNT_Q     128
#define CNT_H1    160
#define CNT_GLOG  208

__device__ __forceinline__ float sigmoidf_(float x) { return 1.f / (1.f + expf(-x)); }

// ---------------- init ----------------
__global__ __launch_bounds__(256) void k_init(const float* __restrict__ h0,
                                              const float* __restrict__ c0,
                                              float* __restrict__ ws) {
  int idx = blockIdx.x * 256 + threadIdx.x, stride = gridDim.x * 256;
  float* inpT = ws + OFF_XT;
  float* hA = ws + OFF_HA;
  float* cT = ws + OFF_CT;
  float* maskT = ws + OFF_MASKT;
  float* buf = ws + OFF_BUF;
  float* bufT = ws + OFF_BUFT;
  int* cnt = (int*)(ws + OFF_CNT);
  for (int i = idx; i < 512 * 64; i += stride) inpT[i] = 0.f;
  for (int i = idx; i < NV * 64; i += stride) maskT[i] = 0.f;
  for (int i = idx; i < B64 * TT * ED; i += stride) { buf[i] = 0.f; bufT[i] = 0.f; }
  for (int i = idx; i < HD * 64; i += stride) {
    int u = i >> 6, b = i & 63;
    hA[i] = h0[b * HD + u];
    cT[i] = c0[b * HD + u];
  }
  if (idx < 521) cnt[idx] = 0;
}

// ---------------- gates GEMM (6 K-splits) + last-block LSTM pointwise tail ----------------
// block (x,y): x = u-group (8 h-units, 32 gate rows: gate g = local row>>3), y = K-split.
__global__ __launch_bounds__(256) void k_gates(const float* __restrict__ inpT,
                                               const float* __restrict__ h_in,
                                               const float* __restrict__ w_ih,
                                               const float* __restrict__ w_hh,
                                               const float* __restrict__ b_ih,
                                               const float* __restrict__ b_hh,
                                               float* __restrict__ gpart, int* __restrict__ cnt,
                                               float* __restrict__ cT, float* __restrict__ h_out) {
  __shared__ float wl[32][256];
  __shared__ int lastf;
  int tid = threadIdx.x;
  int x = blockIdx.x;  // 0..127
  int y = blockIdx.y;  // 0..5
  int u0 = x * 8;
  const float* W;
  const float* xbase;
  int ldW, k0;
  if (y < 2) { W = w_ih; ldW = 512; k0 = y * 256; xbase = inpT + (size_t)k0 * 64; }
  else { W = w_hh; ldW = 1024; k0 = (y - 2) * 256; xbase = h_in + (size_t)k0 * 64; }
  for (int i = tid; i < 32 * 64; i += 256) {
    int r = i >> 6, kk = (i & 63) * 4;
    int grow = (r >> 3) * 1024 + u0 + (r & 7);
    *(float4*)&wl[r][kk] = *(const float4*)&W[(size_t)grow * ldW + k0 + kk];
  }
  __syncthreads();
  int lane = tid & 63, wid = tid >> 6;
  const float* xp = xbase + lane;
  float acc[8] = {0, 0, 0, 0, 0, 0, 0, 0};
#pragma unroll 2
  for (int k4 = 0; k4 < 64; ++k4) {
    float x0 = xp[(4 * k4 + 0) * 64];
    float x1 = xp[(4 * k4 + 1) * 64];
    float x2 = xp[(4 * k4 + 2) * 64];
    float x3 = xp[(4 * k4 + 3) * 64];
#pragma unroll
    for (int i = 0; i < 8; ++i) {
      const float4 w4 = *(const float4*)&wl[wid * 8 + i][4 * k4];
      acc[i] = fmaf(w4.x, x0, acc[i]);
      acc[i] = fmaf(w4.y, x1, acc[i]);
      acc[i] = fmaf(w4.z, x2, acc[i]);
      acc[i] = fmaf(w4.w, x3, acc[i]);
    }
  }
  float* o = gpart + (size_t)y * 262144 + (size_t)(x * 32 + wid * 8) * 64 + lane;
#pragma unroll
  for (int i = 0; i < 8; ++i) o[i * 64] = acc[i];
  // ---- last-arrival tail: combine 6 partials + LSTM pointwise for u0..u0+7 ----
  __threadfence();
  if (tid == 0) lastf = (atomicAdd(&cnt[x], 1) == 5);
  __syncthreads();
  if (!lastf) return;
  if (tid == 0) cnt[x] = 0;
  __threadfence();
  for (int e = tid; e < 512; e += 256) {
    int uloc = e >> 6, b = e & 63;
    int u = u0 + uloc;
    float g4[4];
#pragma unroll
    for (int g = 0; g < 4; ++g) {
      int grow = g * 1024 + u;
      float v = b_ih[grow] + b_hh[grow];
      size_t base = (size_t)(x * 32 + g * 8 + uloc) * 64 + b;
#pragma unroll
      for (int yy = 0; yy < 6; ++yy) v += gpart[(size_t)yy * 262144 + base];
      g4[g] = v;
    }
    float c = cT[u * 64 + b];
    float cn = sigmoidf_(g4[1]) * c + sigmoidf_(g4[0]) * tanhf(g4[2]);
    float hn = sigmoidf_(g4[3]) * tanhf(cn);
    cT[u * 64 + b] = cn;
    h_out[u * 64 + b] = hn;
  }
}

// ---------------- q GEMM (8 K-splits) + last-block combine+transpose tail -> qf[b][h] ----------------
__global__ __launch_bounds__(256) void k_qgemm(const float* __restrict__ hT,
                                               const float* __restrict__ w_q,
                                               const float* __restrict__ b_q,
                                               float* __restrict__ qpart, int* __restrict__ cnt,
                                               float* __restrict__ qf) {
  __shared__ float wl[32][128];
  __shared__ int lastf;
  int tid = threadIdx.x;
  int x = blockIdx.x;  // 0..31 (32-row group)
  int s = blockIdx.y;  // 0..7
  int r0b = x * 32;
  int k0 = s * 128;
  for (int i = tid; i < 32 * 32; i += 256) {
    int r = i >> 5, kk = (i & 31) * 4;
    *(float4*)&wl[r][kk] = *(const float4*)&w_q[(size_t)(r0b + r) * 1024 + k0 + kk];
  }
  __syncthreads();
  int lane = tid & 63, wid = tid >> 6;
  const float* xp = hT + (size_t)k0 * 64 + lane;
  float acc[8] = {0, 0, 0, 0, 0, 0, 0, 0};
#pragma unroll 2
  for (int k4 = 0; k4 < 32; ++k4) {
    float x0 = xp[(4 * k4 + 0) * 64];
    float x1 = xp[(4 * k4 + 1) * 64];
    float x2 = xp[(4 * k4 + 2) * 64];
    float x3 = xp[(4 * k4 + 3) * 64];
#pragma unroll
    for (int i = 0; i < 8; ++i) {
      const float4 w4 = *(const float4*)&wl[wid * 8 + i][4 * k4];
      acc[i] = fmaf(w4.x, x0, acc[i]);
      acc[i] = fmaf(w4.y, x1, acc[i]);
      acc[i] = fmaf(w4.z, x2, acc[i]);
      acc[i] = fmaf(w4.w, x3, acc[i]);
    }
  }
  float* o = qpart + (size_t)s * 65536 + (size_t)(r0b + wid * 8) * 64 + lane;
#pragma unroll
  for (int i = 0; i < 8; ++i) o[i * 64] = acc[i];
  // ---- last-arrival tail: combine 8 splits + b_q, transpose via LDS -> qf[b][h] ----
  __threadfence();
  if (tid == 0) lastf = (atomicAdd(&cnt[CNT_Q + x], 1) == 7);
  __syncthreads();
  if (!lastf) return;
  if (tid == 0) cnt[CNT_Q + x] = 0;
  __threadfence();
  float* t2 = &wl[0][0];  // reuse LDS: 32x65 = 2080 floats <= 4096
  for (int e = tid; e < 2048; e += 256) {
    int hloc = e >> 6, b = e & 63;
    int h = r0b + hloc;
    float v = b_q[h];
#pragma unroll
    for (int ss = 0; ss < 8; ++ss) v += qpart[(size_t)ss * 65536 + (size_t)h * 64 + b];
    t2[hloc * 65 + b] = v;
  }
  __syncthreads();
  for (int e = tid; e < 2048; e += 256) {
    int b = e >> 5, hloc = e & 31;
    qf[(size_t)b * 1024 + r0b + hloc] = t2[hloc * 65 + b];
  }
}

// ---------------- flash attention: 16 s-splits, 8 rows/wave, pair-pipelined (R4-proven) ----------------
__global__ __launch_bounds__(256) void k_flash(const float* __restrict__ enc,
                                               const int* __restrict__ tlen,
                                               const float* __restrict__ qf,
                                               float* __restrict__ fm, float* __restrict__ fl,
                                               float* __restrict__ facc) {
  __shared__ float lacc[4][1024];
  __shared__ float lml[4][2];
  int b = blockIdx.x >> 4, split = blockIdx.x & 15;
  int tid = threadIdx.x, lane = tid & 63, wid = tid >> 6;
  int len = tlen[b];
  float qv[16];
#pragma unroll
  for (int j = 0; j < 4; ++j) {
    float4 tq = *(const float4*)&qf[(size_t)b * 1024 + j * 256 + lane * 4];
    qv[4 * j + 0] = tq.x; qv[4 * j + 1] = tq.y; qv[4 * j + 2] = tq.z; qv[4 * j + 3] = tq.w;
  }
  const float* base = enc + (size_t)b * SE * HD;
  int s0 = split * 32 + wid * 8;
  int nr = len - s0;
  nr = nr < 0 ? 0 : (nr > 8 ? 8 : nr);
  int npair = nr >> 1;

  float4 cA[4], cB[4], nA[4], nB[4];
  float m = -1e30f, l = 0.f, acc[16];
#pragma unroll
  for (int j = 0; j < 16; ++j) acc[j] = 0.f;

#define LOADROW(d, s)                                                 \
  {                                                                   \
    const float4* rp = (const float4*)(base + (size_t)(s)*HD) + lane; \
    d[0] = rp[0]; d[1] = rp[64]; d[2] = rp[128]; d[3] = rp[192];      \
  }

  if (npair > 0) { LOADROW(cA, s0); LOADROW(cB, s0 + 1); }
  for (int p = 0; p < npair; ++p) {
    if (p + 1 < npair) {
      LOADROW(nA, s0 + 2 * p + 2);
      LOADROW(nB, s0 + 2 * p + 3);
    } else if (nr & 1) {
      LOADROW(nA, s0 + nr - 1);
    }
    float d0 = 0.f, d1 = 0.f;
#pragma unroll
    for (int j = 0; j < 4; ++j) {
      d0 = fmaf(qv[4 * j + 0], cA[j].x, d0); d1 = fmaf(qv[4 * j + 0], cB[j].x, d1);
      d0 = fmaf(qv[4 * j + 1], cA[j].y, d0); d1 = fmaf(qv[4 * j + 1], cB[j].y, d1);
      d0 = fmaf(qv[4 * j + 2], cA[j].z, d0); d1 = fmaf(qv[4 * j + 2], cB[j].z, d1);
      d0 = fmaf(qv[4 * j + 3], cA[j].w, d0); d1 = fmaf(qv[4 * j + 3], cB[j].w, d1);
    }
#pragma unroll
    for (int off = 32; off; off >>= 1) { d0 += __shfl_xor(d0, off, 64); d1 += __shfl_xor(d1, off, 64); }
    d0 = __shfl(d0, 0, 64);
    d1 = __shfl(d1, 0, 64);
    float mn = fmaxf(m, fmaxf(d0, d1));
    float sc = expf(m - mn), p0 = expf(d0 - mn), p1 = expf(d1 - mn);
    l = l * sc + p0 + p1;
#pragma unroll
    for (int j = 0; j < 4; ++j) {
      acc[4 * j + 0] = fmaf(p1, cB[j].x, fmaf(p0, cA[j].x, acc[4 * j + 0] * sc));
      acc[4 * j + 1] = fmaf(p1, cB[j].y, fmaf(p0, cA[j].y, acc[4 * j + 1] * sc));
      acc[4 * j + 2] = fmaf(p1, cB[j].z, fmaf(p0, cA[j].z, acc[4 * j + 2] * sc));
      acc[4 * j + 3] = fmaf(p1, cB[j].w, fmaf(p0, cA[j].w, acc[4 * j + 3] * sc));
    }
    m = mn;
#pragma unroll
    for (int j = 0; j < 4; ++j) { cA[j] = nA[j]; cB[j] = nB[j]; }
  }
  if (nr & 1) {
    if (npair == 0) LOADROW(cA, s0);
    float d0 = 0.f;
#pragma unroll
    for (int j = 0; j < 4; ++j) {
      d0 = fmaf(qv[4 * j + 0], cA[j].x, d0);
      d0 = fmaf(qv[4 * j + 1], cA[j].y, d0);
      d0 = fmaf(qv[4 * j + 2], cA[j].z, d0);
      d0 = fmaf(qv[4 * j + 3], cA[j].w, d0);
    }
#pragma unroll
    for (int off = 32; off; off >>= 1) d0 += __shfl_xor(d0, off, 64);
    d0 = __shfl(d0, 0, 64);
    float mn = fmaxf(m, d0);
    float sc = expf(m - mn), p0 = expf(d0 - mn);
    l = l * sc + p0;
#pragma unroll
    for (int j = 0; j < 4; ++j) {
      acc[4 * j + 0] = fmaf(p0, cA[j].x, acc[4 * j + 0] * sc);
      acc[4 * j + 1] = fmaf(p0, cA[j].y, acc[4 * j + 1] * sc);
      acc[4 * j + 2] = fmaf(p0, cA[j].z, acc[4 * j + 2] * sc);
      acc[4 * j + 3] = fmaf(p0, cA[j].w, acc[4 * j + 3] * sc);
    }
    m = mn;
  }
#undef LOADROW
#pragma unroll
  for (int j = 0; j < 4; ++j)
    *(float4*)&lacc[wid][j * 256 + lane * 4] =
        make_float4(acc[4 * j], acc[4 * j + 1], acc[4 * j + 2], acc[4 * j + 3]);
  if (lane == 0) { lml[wid][0] = m; lml[wid][1] = l; }
  __syncthreads();
  float M = fmaxf(fmaxf(lml[0][0], lml[1][0]), fmaxf(lml[2][0], lml[3][0]));
  float w0 = expf(lml[0][0] - M), w1 = expf(lml[1][0] - M);
  float w2 = expf(lml[2][0] - M), w3 = expf(lml[3][0] - M);
  float L = w0 * lml[0][1] + w1 * lml[1][1] + w2 * lml[2][1] + w3 * lml[3][1];
  int p = b * 16 + split;
  for (int h = tid; h < 1024; h += 256)
    facc[(size_t)p * 1024 + h] =
        w0 * lacc[0][h] + w1 * lacc[1][h] + w2 * lacc[2][h] + w3 * lacc[3][h];
  if (tid == 0) { fm[p] = M; fl[p] = L; }
}

// ---------------- fused: flash combine (16) + history softmax (wave-parallel) -> xT2 ----------------
__global__ __launch_bounds__(256) void k_ctx(const float* __restrict__ enc,
                                             const float* __restrict__ fm,
                                             const float* __restrict__ fl,
                                             const float* __restrict__ facc,
                                             const float* __restrict__ kvp,
                                             const float* __restrict__ b_ko,
                                             const float* __restrict__ buf,
                                             const float* __restrict__ inpT,
                                             float* __restrict__ xT2, int tv) {
  __shared__ float pw[TT];
  int b = blockIdx.x, tid = threadIdx.x, lane = tid & 63, wid = tid >> 6;
  // history scores: wave wid handles k = wid, wid+4, ...; lanes gather 64 groups, butterfly sum
  for (int k = wid; k < tv; k += 4) {
    float v = kvp[((size_t)lane * TT + k) * 64 + b];
#pragma unroll
    for (int off = 32; off; off >>= 1) v += __shfl_xor(v, off, 64);
    if (lane == 0) pw[k] = v + b_ko[0];
  }
  __syncthreads();
  float mx = -1e30f;
  for (int k = 0; k < tv; ++k) mx = fmaxf(mx, pw[k]);
  float den = 0.f;
  for (int k = 0; k < tv; ++k) den += expf(pw[k] - mx);
  float invd = 1.f / den;
  __syncthreads();
  if (tid < tv) pw[tid] = expf(pw[tid] - mx) * invd;
  __syncthreads();
  float M = -1e30f;
#pragma unroll
  for (int k = 0; k < 16; ++k) M = fmaxf(M, fm[b * 16 + k]);
  float w[16];
  float L = 0.f;
#pragma unroll
  for (int k = 0; k < 16; ++k) {
    w[k] = expf(fm[b * 16 + k] - M);
    L += w[k] * fl[b * 16 + k];
  }
  float inv = 1.f / L;
  for (int h = tid; h < 1024; h += 256) {
    float s = 0.f;
#pragma unroll
    for (int k = 0; k < 16; ++k) s += w[k] * facc[(size_t)(b * 16 + k) * 1024 + h];
    xT2[h * 64 + b] = enc[(size_t)b * SE * HD + h] + s * inv;  // sent = enc[:,0,:]
  }
  for (int e = tid; e < 512; e += 256) {
    float a = 0.f;
    for (int k = 0; k < tv; ++k) a += pw[k] * buf[((size_t)b * TT + k) * 512 + e];
    xT2[(1024 + e) * 64 + b] = inpT[e * 64 + b] + a;
  }
}

// ---------------- h1 GEMM (12 K-splits) + last-block bias+relu tail -> h1T ----------------
__global__ __launch_bounds__(256) void k_h1(const float* __restrict__ xT2,
                                            const float* __restrict__ w_m1,
                                            const float* __restrict__ b_m1,
                                            float* __restrict__ h1part, int* __restrict__ cnt,
                                            float* __restrict__ h1T) {
  __shared__ float wl[32][128];
  __shared__ int lastf;
  int tid = threadIdx.x;
  int x = blockIdx.x;  // 0..47
  int s = blockIdx.y;  // 0..11
  int r0b = x * 32;
  int k0 = s * 128;
  for (int i = tid; i < 32 * 32; i += 256) {
    int r = i >> 5, kk = (i & 31) * 4;
    *(float4*)&wl[r][kk] = *(const float4*)&w_m1[(size_t)(r0b + r) * MM + k0 + kk];
  }
  __syncthreads();
  int lane = tid & 63, wid = tid >> 6;
  const float* xp = xT2 + (size_t)k0 * 64 + lane;
  float acc[8] = {0, 0, 0, 0, 0, 0, 0, 0};
#pragma unroll 2
  for (int k4 = 0; k4 < 32; ++k4) {
    float x0 = xp[(4 * k4 + 0) * 64];
    float x1 = xp[(4 * k4 + 1) * 64];
    float x2 = xp[(4 * k4 + 2) * 64];
    float x3 = xp[(4 * k4 + 3) * 64];
#pragma unroll
    for (int i = 0; i < 8; ++i) {
      const float4 w4 = *(const float4*)&wl[wid * 8 + i][4 * k4];
      acc[i] = fmaf(w4.x, x0, acc[i]);
      acc[i] = fmaf(w4.y, x1, acc[i]);
      acc[i] = fmaf(w4.z, x2, acc[i]);
      acc[i] = fmaf(w4.w, x3, acc[i]);
    }
  }
  float* o = h1part + (size_t)s * 98304 + (size_t)(r0b + wid * 8) * 64 + lane;
#pragma unroll
  for (int i = 0; i < 8; ++i) o[i * 64] = acc[i];
  // ---- tail: combine 12 partials + bias + relu ----
  __threadfence();
  if (tid == 0) lastf = (atomicAdd(&cnt[CNT_H1 + x], 1) == 11);
  __syncthreads();
  if (!lastf) return;
  if (tid == 0) cnt[CNT_H1 + x] = 0;
  __threadfence();
  for (int e = tid; e < 2048; e += 256) {
    int rloc = e >> 6, b = e & 63;
    int r = r0b + rloc;
    float v = b_m1[r];
#pragma unroll
    for (int ss = 0; ss < 12; ++ss) v += h1part[(size_t)ss * 98304 + (size_t)r * 64 + b];
    h1T[(size_t)r * 64 + b] = fmaxf(v, 0.f);
  }
}

// ---------------- vocab GEMM (6 K-splits) + last-block logits-finish tail ----------------
__global__ __launch_bounds__(256) void k_glogfin(const float* __restrict__ h1T,
                                                 const float* __restrict__ w_m2,
                                                 const float* __restrict__ b_m2,
                                                 const float* __restrict__ maskT,
                                                 float* __restrict__ lp, int* __restrict__ cnt,
                                                 float* __restrict__ argv, int* __restrict__ argi,
                                                 float* __restrict__ out, int t) {
  __shared__ float wl[32][256];
  __shared__ int lastf;
  int tid = threadIdx.x;
  int x = blockIdx.x;  // 0..312
  int s = blockIdx.y;  // 0..5
  int r0b = x * 32;
  int k0 = s * 256;
  for (int i = tid; i < 32 * 64; i += 256) {
    int r = i >> 6, kk = (i & 63) * 4;
    int gr = r0b + r;
    if (gr > NV - 1) gr = NV - 1;
    *(float4*)&wl[r][kk] = *(const float4*)&w_m2[(size_t)gr * MM + k0 + kk];
  }
  __syncthreads();
  int lane = tid & 63, wid = tid >> 6;
  const float* xp = h1T + (size_t)k0 * 64 + lane;
  float acc[8] = {0, 0, 0, 0, 0, 0, 0, 0};
#pragma unroll 2
  for (int k4 = 0; k4 < 64; ++k4) {
    float x0 = xp[(4 * k4 + 0) * 64];
    float x1 = xp[(4 * k4 + 1) * 64];
    float x2 = xp[(4 * k4 + 2) * 64];
    float x3 = xp[(4 * k4 + 3) * 64];
#pragma unroll
    for (int i = 0; i < 8; ++i) {
      const float4 w4 = *(const float4*)&wl[wid * 8 + i][4 * k4];
      acc[i] = fmaf(w4.x, x0, acc[i]);
      acc[i] = fmaf(w4.y, x1, acc[i]);
      acc[i] = fmaf(w4.z, x2, acc[i]);
      acc[i] = fmaf(w4.w, x3, acc[i]);
    }
  }
  int r0 = r0b + wid * 8;
  float* o = lp + (size_t)s * 640000 + (size_t)r0 * 64 + lane;
#pragma unroll
  for (int i = 0; i < 8; ++i)
    if (r0 + i < NV) o[i * 64] = acc[i];
  // ---- tail: combine 6 partials + bias + mask + argmax partials + transposed out-write ----
  __threadfence();
  if (tid == 0) lastf = (atomicAdd(&cnt[CNT_GLOG + x], 1) == 5);
  __syncthreads();
  if (!lastf) return;
  if (tid == 0) cnt[CNT_GLOG + x] = 0;
  __threadfence();
  float* tile = &wl[0][0];  // reuse LDS: 32x65 = 2080 floats <= 8192
  for (int e = tid; e < 2048; e += 256) {
    int rloc = e >> 6, b = e & 63;
    int r = r0b + rloc;
    if (r < NV) {
      float v = b_m2[r] + maskT[(size_t)r * 64 + b];
#pragma unroll
      for (int ss = 0; ss < 6; ++ss) v += lp[(size_t)ss * 640000 + (size_t)r * 64 + b];
      tile[rloc * 65 + b] = v;
    }
  }
  __syncthreads();
  int rg = x * 4 + wid;
  if (rg < 1250) {
    float best = -3.4e38f;
    int bi = 0;
#pragma unroll
    for (int i = 0; i < 8; ++i) {
      float v = tile[(wid * 8 + i) * 65 + lane];
      if (v > best) { best = v; bi = rg * 8 + i; }  // strict >: first-max
    }
    argv[(size_t)rg * 64 + lane] = best;
    argi[(size_t)rg * 64 + lane] = bi;
  }
  int b = tid >> 2, q = tid & 3;
  int nloc = q * 8;
  if (r0b + nloc < NV) {
    float tmp[8];
#pragma unroll
    for (int c = 0; c < 8; ++c) tmp[c] = tile[(nloc + c) * 65 + b];
    float4* op = (float4*)&out[((size_t)b * TT + t) * NV + r0b + nloc];
    op[0] = make_float4(tmp[0], tmp[1], tmp[2], tmp[3]);
    op[1] = make_float4(tmp[4], tmp[5], tmp[6], tmp[7]);
  }
}

// ---------------- final argmax (per-batch block) + feedback ----------------
__global__ __launch_bounds__(256) void k_final(const float* __restrict__ argv,
                                               const int* __restrict__ argi,
                                               const float* __restrict__ emb,
                                               float* __restrict__ maskT, float* __restrict__ inpT,
                                               float* __restrict__ buf, float* __restrict__ bufT,
                                               float* __restrict__ out_ids, int t) {
  __shared__ float sv[256];
  __shared__ int si_[256];
  __shared__ int sid;
  int b = blockIdx.x, tid = threadIdx.x;
  float best = -3.4e38f;
  int bi = 0x7fffffff;
  for (int g = tid; g < 1250; g += 256) {
    float v = argv[(size_t)g * 64 + b];
    int idx = argi[(size_t)g * 64 + b];
    if (v > best || (v == best && idx < bi)) { best = v; bi = idx; }
  }
  sv[tid] = best;
  si_[tid] = bi;
  __syncthreads();
  for (int off = 128; off; off >>= 1) {
    if (tid < off) {
      float v2 = sv[tid + off];
      int i2 = si_[tid + off];
      if (v2 > sv[tid] || (v2 == sv[tid] && i2 < si_[tid])) { sv[tid] = v2; si_[tid] = i2; }
    }
    __syncthreads();
  }
  if (tid == 0) {
    sid = si_[0];
    out_ids[b * TT + t] = (float)si_[0];
    if (si_[0] != 1) maskT[(size_t)si_[0] * 64 + b] = MASK_VALF;  // EOS(1) stays 0
  }
  __syncthreads();
  int id = sid;
  for (int e = tid; e < 512; e += 256) {
    float v = emb[(size_t)id * 512 + e];
    inpT[e * 64 + b] = v;
    buf[((size_t)b * TT + t) * 512 + e] = v;
    bufT[(size_t)e * (TT * 64) + t * 64 + b] = v;
  }
}

// ---------------- incremental history score for buf column j ----------------
__global__ __launch_bounds__(256) void k_kscore(const float* __restrict__ bufT,
                                                const float* __restrict__ w_k,
                                                const float* __restrict__ b_k,
                                                const float* __restrict__ w_ko,
                                                float* __restrict__ kvp, int j) {
  __shared__ float sacc[4][8][64];
  int lane = threadIdx.x & 63, wid = threadIdx.x >> 6;
  int ug = blockIdx.x;  // 0..63
  int u0 = ug * 8;
  int k0 = wid * 128;
  const float* xp = bufT + (size_t)j * 64 + lane;
  float acc[8] = {0, 0, 0, 0, 0, 0, 0, 0};
  for (int k4 = 0; k4 < 32; ++k4) {
    int e = k0 + 4 * k4;
    float x0 = xp[(size_t)(e + 0) * (TT * 64)];
    float x1 = xp[(size_t)(e + 1) * (TT * 64)];
    float x2 = xp[(size_t)(e + 2) * (TT * 64)];
    float x3 = xp[(size_t)(e + 3) * (TT * 64)];
#pragma unroll
    for (int i = 0; i < 8; ++i) {
      const float4 w4 = *(const float4*)&w_k[(size_t)(u0 + i) * 512 + e];
      acc[i] = fmaf(w4.x, x0, acc[i]);
      acc[i] = fmaf(w4.y, x1, acc[i]);
      acc[i] = fmaf(w4.z, x2, acc[i]);
      acc[i] = fmaf(w4.w, x3, acc[i]);
    }
  }
#pragma unroll
  for (int i = 0; i < 8; ++i) sacc[wid][i][lane] = acc[i];
  __syncthreads();
  if (wid == 0) {
    float kp = 0.f;
#pragma unroll
    for (int i = 0; i < 8; ++i) {
      float tot = b_k[u0 + i] + sacc[0][i][lane] + sacc[1][i][lane] + sacc[2][i][lane] +
                  sacc[3][i][lane];
      kp += fmaxf(tot, 0.f) * w_ko[u0 + i];
    }
    kvp[((size_t)ug * TT + j) * 64 + lane] = kp;
  }
}

extern "C" void kernel_launch(void* const* d_in, const int* in_sizes, int n_in,
                              void* d_out, int out_size, void* d_ws, size_t ws_size,
                              hipStream_t stream) {
  const float* enc = (const float*)d_in[0];
  const float* h0 = (const float*)d_in[1];
  const float* c0 = (const float*)d_in[2];
  const int* tlen = (const int*)d_in[3];
  const float* emb = (const float*)d_in[5];
  const float* w_ih = (const float*)d_in[6];
  const float* w_hh = (const float*)d_in[7];
  const float* b_ih = (const float*)d_in[8];
  const float* b_hh = (const float*)d_in[9];
  const float* w_q = (const float*)d_in[10];
  const float* b_q = (const float*)d_in[11];
  const float* w_k = (const float*)d_in[12];
  const float* b_k = (const float*)d_in[13];
  const float* w_ko = (const float*)d_in[14];
  const float* b_ko = (const float*)d_in[15];
  const float* w_m1 = (const float*)d_in[16];
  const float* b_m1 = (const float*)d_in[17];
  const float* w_m2 = (const float*)d_in[18];
  const float* b_m2 = (const float*)d_in[19];

  float* ws = (float*)d_ws;
  float* out_logits = (float*)d_out;
  float* out_ids = out_logits + (size_t)B64 * TT * NV;

  float* inpT = ws + OFF_XT;
  float* hA = ws + OFF_HA;
  float* hB = ws + OFF_HB;
  int* cnt = (int*)(ws + OFF_CNT);

  k_init<<<2048, 256, 0, stream>>>(h0, c0, ws);
  k_kscore<<<64, 256, 0, stream>>>(ws + OFF_BUFT, w_k, b_k, w_ko, ws + OFF_KVP, 0);

  for (int t = 0; t < TT; ++t) {
    int tv = (t < 1) ? 1 : t;
    float* h_in = (t & 1) ? hB : hA;
    float* h_out = (t & 1) ? hA : hB;
    k_gates<<<dim3(128, 6), 256, 0, stream>>>(inpT, h_in, w_ih, w_hh, b_ih, b_hh, ws + OFF_A,
                                              cnt + CNT_GATES, ws + OFF_CT, h_out);
    k_qgemm<<<dim3(32, 8), 256, 0, stream>>>(h_out, w_q, b_q, ws + OFF_QP, cnt, ws + OFF_QF);
    k_flash<<<1024, 256, 0, stream>>>(enc, tlen, ws + OFF_QF, ws + OFF_FM, ws + OFF_FL,
                                      ws + OFF_FACC);
    k_ctx<<<64, 256, 0, stream>>>(enc, ws + OFF_FM, ws + OFF_FL, ws + OFF_FACC, ws + OFF_KVP,
                                  b_ko, ws + OFF_BUF, inpT, ws + OFF_XT2, tv);
    k_h1<<<dim3(48, 12), 256, 0, stream>>>(ws + OFF_XT2, w_m1, b_m1, ws + OFF_A, cnt,
                                           ws + OFF_H1T);
    k_glogfin<<<dim3(313, 6), 256, 0, stream>>>(ws + OFF_H1T, w_m2, b_m2, ws + OFF_MASKT,
                                                ws + OFF_A, cnt, ws + OFF_ARGV,
                                                (int*)(ws + OFF_ARGI), out_logits, t);
    k_final<<<64, 256, 0, stream>>>(ws + OFF_ARGV, (int*)(ws + OFF_ARGI), emb, ws + OFF_MASKT,
                                    inpT, ws + OFF_BUF, ws + OFF_BUFT, out_ids, t);
    if (t < TT - 1)
      k_kscore<<<64, 256, 0, stream>>>(ws + OFF_BUFT, w_k, b_k, w_ko, ws + OFF_KVP, t);
  }
}

// Round 8
// 3491.082 us; speedup vs baseline: 2.9847x; 2.9847x over previous
//
#include <hip/hip_runtime.h>

#define B64 64
#define SE 512
#define HD 1024
#define ED 512
#define NV 10000
#define TT 20
#define MM 1536
#define MASK_VALF -10000000.0f

// ---- workspace offsets (floats) ----
#define OFF_XA    0          // [inp(512) | h(1024)] x 64, parity A
#define OFF_XB    98304      // parity B
#define OFF_CT    196608     // cT [1024][64]
#define OFF_QF    262144     // qf [64][1024]
#define OFF_FM    327680     // [1024]
#define OFF_FL    328704     // [1024]
#define OFF_FACC  329728     // [1024][1024]
#define OFF_XT2   1378304    // [1536][64]
#define OFF_H1T   1476608    // [1536][64]
#define OFF_ARGV  1574912    // [1250][64]
#define OFF_ARGI  1654912    // [1250][64] (int)
#define OFF_MASKT 1734912    // [10000][64]
#define OFF_BUF   2374912    // [64][20][512]
#define OFF_BUFT  3030272    // [512][20][64]
#define OFF_KVP   3685632    // [64][20][64]
// end: 3767552 floats ~= 15.1 MB

__device__ __forceinline__ float sigmoidf_(float x) { return 1.f / (1.f + expf(-x)); }

// ---------------- init ----------------
__global__ __launch_bounds__(256) void k_init(const float* __restrict__ h0,
                                              const float* __restrict__ c0,
                                              float* __restrict__ ws) {
  int idx = blockIdx.x * 256 + threadIdx.x, stride = gridDim.x * 256;
  float* xa = ws + OFF_XA;
  float* cT = ws + OFF_CT;
  float* maskT = ws + OFF_MASKT;
  float* buf = ws + OFF_BUF;
  float* bufT = ws + OFF_BUFT;
  for (int i = idx; i < 512 * 64; i += stride) xa[i] = 0.f;  // inp section
  for (int i = idx; i < NV * 64; i += stride) maskT[i] = 0.f;
  for (int i = idx; i < B64 * TT * ED; i += stride) { buf[i] = 0.f; bufT[i] = 0.f; }
  for (int i = idx; i < HD * 64; i += stride) {
    int u = i >> 6, b = i & 63;
    xa[512 * 64 + i] = h0[b * HD + u];  // h section
    cT[i] = c0[b * HD + u];
  }
}

// ---------------- fused LSTM cell: intra-block split-K (4 waves x K/4) + pointwise ----------------
// block = 2 u's x 4 gates (8 rows). Each wave computes ALL 8 rows over its K-quarter (ILP 8),
// waves LDS-reduce, tail does the LSTM pointwise. x = [inp(512)|h(1024)] unified buffer.
__global__ __launch_bounds__(256) void k_cell(const float* __restrict__ xcur,
                                              const float* __restrict__ w_ih,
                                              const float* __restrict__ w_hh,
                                              const float* __restrict__ b_ih,
                                              const float* __restrict__ b_hh,
                                              float* __restrict__ cT,
                                              float* __restrict__ xnext) {
  __shared__ float wl[8 * 1536];  // 48 KB; reused for cross-wave reduce
  int tid = threadIdx.x;
  int u0 = blockIdx.x * 2;
  for (int i = tid; i < 3072; i += 256) {
    int lr = i / 384, kq = i % 384;
    int k = kq * 4;
    int grow = (lr >> 1) * 1024 + u0 + (lr & 1);
    float4 v;
    if (k < 512) v = *(const float4*)&w_ih[(size_t)grow * 512 + k];
    else v = *(const float4*)&w_hh[(size_t)grow * 1024 + (k - 512)];
    *(float4*)&wl[lr * 1536 + k] = v;
  }
  __syncthreads();
  int lane = tid & 63, wid = tid >> 6;
  int kbase = wid * 384;
  const float* xp = xcur + (size_t)kbase * 64 + lane;
  float acc[8] = {0, 0, 0, 0, 0, 0, 0, 0};
#pragma unroll 2
  for (int k4 = 0; k4 < 96; ++k4) {
    float x0 = xp[(4 * k4 + 0) * 64];
    float x1 = xp[(4 * k4 + 1) * 64];
    float x2 = xp[(4 * k4 + 2) * 64];
    float x3 = xp[(4 * k4 + 3) * 64];
#pragma unroll
    for (int lr = 0; lr < 8; ++lr) {
      const float4 w4 = *(const float4*)&wl[lr * 1536 + kbase + 4 * k4];
      acc[lr] = fmaf(w4.x, x0, acc[lr]);
      acc[lr] = fmaf(w4.y, x1, acc[lr]);
      acc[lr] = fmaf(w4.z, x2, acc[lr]);
      acc[lr] = fmaf(w4.w, x3, acc[lr]);
    }
  }
  __syncthreads();  // weights dead; reuse wl for reduce
#pragma unroll
  for (int lr = 0; lr < 8; ++lr) wl[wid * 512 + lr * 64 + lane] = acc[lr];
  __syncthreads();
  if (tid < 128) {
    int j = tid >> 6, b = tid & 63;
    float g4[4];
#pragma unroll
    for (int g = 0; g < 4; ++g) {
      int lr = g * 2 + j;
      int grow = g * 1024 + u0 + j;
      float v = b_ih[grow] + b_hh[grow];
#pragma unroll
      for (int w = 0; w < 4; ++w) v += wl[w * 512 + lr * 64 + b];  // fixed order: deterministic
      g4[g] = v;
    }
    int u = u0 + j;
    float c = cT[u * 64 + b];
    float cn = sigmoidf_(g4[1]) * c + sigmoidf_(g4[0]) * tanhf(g4[2]);
    float hn = sigmoidf_(g4[3]) * tanhf(cn);
    cT[u * 64 + b] = cn;
    xnext[(512 + u) * 64 + b] = hn;
  }
}

// ---------------- fused q GEMM: intra-block split-K + combine -> qf[b][h] ----------------
__global__ __launch_bounds__(256) void k_q2(const float* __restrict__ h,
                                            const float* __restrict__ w_q,
                                            const float* __restrict__ b_q,
                                            float* __restrict__ qf) {
  __shared__ float wl[8 * 1024];  // 32 KB
  int tid = threadIdx.x;
  int h0 = blockIdx.x * 8;
  for (int i = tid; i < 2048; i += 256) {
    int lr = i >> 8, kq = i & 255;
    *(float4*)&wl[lr * 1024 + kq * 4] = *(const float4*)&w_q[(size_t)(h0 + lr) * 1024 + kq * 4];
  }
  __syncthreads();
  int lane = tid & 63, wid = tid >> 6;
  int kbase = wid * 256;
  const float* xp = h + (size_t)kbase * 64 + lane;
  float acc[8] = {0, 0, 0, 0, 0, 0, 0, 0};
#pragma unroll 2
  for (int k4 = 0; k4 < 64; ++k4) {
    float x0 = xp[(4 * k4 + 0) * 64];
    float x1 = xp[(4 * k4 + 1) * 64];
    float x2 = xp[(4 * k4 + 2) * 64];
    float x3 = xp[(4 * k4 + 3) * 64];
#pragma unroll
    for (int lr = 0; lr < 8; ++lr) {
      const float4 w4 = *(const float4*)&wl[lr * 1024 + kbase + 4 * k4];
      acc[lr] = fmaf(w4.x, x0, acc[lr]);
      acc[lr] = fmaf(w4.y, x1, acc[lr]);
      acc[lr] = fmaf(w4.z, x2, acc[lr]);
      acc[lr] = fmaf(w4.w, x3, acc[lr]);
    }
  }
  __syncthreads();
#pragma unroll
  for (int lr = 0; lr < 8; ++lr) wl[wid * 512 + lr * 64 + lane] = acc[lr];
  __syncthreads();
  for (int e = tid; e < 512; e += 256) {
    int lr = e >> 6, b = e & 63;
    float v = b_q[h0 + lr];
#pragma unroll
    for (int w = 0; w < 4; ++w) v += wl[w * 512 + lr * 64 + b];
    qf[(size_t)b * 1024 + h0 + lr] = v;
  }
}

// ---------------- flash attention: 16 s-splits, 8 rows/wave, pair-pipelined (R4-proven) ----------------
__global__ __launch_bounds__(256) void k_flash(const float* __restrict__ enc,
                                               const int* __restrict__ tlen,
                                               const float* __restrict__ qf,
                                               float* __restrict__ fm, float* __restrict__ fl,
                                               float* __restrict__ facc) {
  __shared__ float lacc[4][1024];
  __shared__ float lml[4][2];
  int b = blockIdx.x >> 4, split = blockIdx.x & 15;
  int tid = threadIdx.x, lane = tid & 63, wid = tid >> 6;
  int len = tlen[b];
  float qv[16];
#pragma unroll
  for (int j = 0; j < 4; ++j) {
    float4 tq = *(const float4*)&qf[(size_t)b * 1024 + j * 256 + lane * 4];
    qv[4 * j + 0] = tq.x; qv[4 * j + 1] = tq.y; qv[4 * j + 2] = tq.z; qv[4 * j + 3] = tq.w;
  }
  const float* base = enc + (size_t)b * SE * HD;
  int s0 = split * 32 + wid * 8;
  int nr = len - s0;
  nr = nr < 0 ? 0 : (nr > 8 ? 8 : nr);
  int npair = nr >> 1;

  float4 cA[4], cB[4], nA[4], nB[4];
  float m = -1e30f, l = 0.f, acc[16];
#pragma unroll
  for (int j = 0; j < 16; ++j) acc[j] = 0.f;

#define LOADROW(d, s)                                                 \
  {                                                                   \
    const float4* rp = (const float4*)(base + (size_t)(s)*HD) + lane; \
    d[0] = rp[0]; d[1] = rp[64]; d[2] = rp[128]; d[3] = rp[192];      \
  }

  if (npair > 0) { LOADROW(cA, s0); LOADROW(cB, s0 + 1); }
  for (int p = 0; p < npair; ++p) {
    if (p + 1 < npair) {
      LOADROW(nA, s0 + 2 * p + 2);
      LOADROW(nB, s0 + 2 * p + 3);
    } else if (nr & 1) {
      LOADROW(nA, s0 + nr - 1);
    }
    float d0 = 0.f, d1 = 0.f;
#pragma unroll
    for (int j = 0; j < 4; ++j) {
      d0 = fmaf(qv[4 * j + 0], cA[j].x, d0); d1 = fmaf(qv[4 * j + 0], cB[j].x, d1);
      d0 = fmaf(qv[4 * j + 1], cA[j].y, d0); d1 = fmaf(qv[4 * j + 1], cB[j].y, d1);
      d0 = fmaf(qv[4 * j + 2], cA[j].z, d0); d1 = fmaf(qv[4 * j + 2], cB[j].z, d1);
      d0 = fmaf(qv[4 * j + 3], cA[j].w, d0); d1 = fmaf(qv[4 * j + 3], cB[j].w, d1);
    }
#pragma unroll
    for (int off = 32; off; off >>= 1) { d0 += __shfl_xor(d0, off, 64); d1 += __shfl_xor(d1, off, 64); }
    d0 = __shfl(d0, 0, 64);
    d1 = __shfl(d1, 0, 64);
    float mn = fmaxf(m, fmaxf(d0, d1));
    float sc = expf(m - mn), p0 = expf(d0 - mn), p1 = expf(d1 - mn);
    l = l * sc + p0 + p1;
#pragma unroll
    for (int j = 0; j < 4; ++j) {
      acc[4 * j + 0] = fmaf(p1, cB[j].x, fmaf(p0, cA[j].x, acc[4 * j + 0] * sc));
      acc[4 * j + 1] = fmaf(p1, cB[j].y, fmaf(p0, cA[j].y, acc[4 * j + 1] * sc));
      acc[4 * j + 2] = fmaf(p1, cB[j].z, fmaf(p0, cA[j].z, acc[4 * j + 2] * sc));
      acc[4 * j + 3] = fmaf(p1, cB[j].w, fmaf(p0, cA[j].w, acc[4 * j + 3] * sc));
    }
    m = mn;
#pragma unroll
    for (int j = 0; j < 4; ++j) { cA[j] = nA[j]; cB[j] = nB[j]; }
  }
  if (nr & 1) {
    if (npair == 0) LOADROW(cA, s0);
    float d0 = 0.f;
#pragma unroll
    for (int j = 0; j < 4; ++j) {
      d0 = fmaf(qv[4 * j + 0], cA[j].x, d0);
      d0 = fmaf(qv[4 * j + 1], cA[j].y, d0);
      d0 = fmaf(qv[4 * j + 2], cA[j].z, d0);
      d0 = fmaf(qv[4 * j + 3], cA[j].w, d0);
    }
#pragma unroll
    for (int off = 32; off; off >>= 1) d0 += __shfl_xor(d0, off, 64);
    d0 = __shfl(d0, 0, 64);
    float mn = fmaxf(m, d0);
    float sc = expf(m - mn), p0 = expf(d0 - mn);
    l = l * sc + p0;
#pragma unroll
    for (int j = 0; j < 4; ++j) {
      acc[4 * j + 0] = fmaf(p0, cA[j].x, acc[4 * j + 0] * sc);
      acc[4 * j + 1] = fmaf(p0, cA[j].y, acc[4 * j + 1] * sc);
      acc[4 * j + 2] = fmaf(p0, cA[j].z, acc[4 * j + 2] * sc);
      acc[4 * j + 3] = fmaf(p0, cA[j].w, acc[4 * j + 3] * sc);
    }
    m = mn;
  }
#undef LOADROW
#pragma unroll
  for (int j = 0; j < 4; ++j)
    *(float4*)&lacc[wid][j * 256 + lane * 4] =
        make_float4(acc[4 * j], acc[4 * j + 1], acc[4 * j + 2], acc[4 * j + 3]);
  if (lane == 0) { lml[wid][0] = m; lml[wid][1] = l; }
  __syncthreads();
  float M = fmaxf(fmaxf(lml[0][0], lml[1][0]), fmaxf(lml[2][0], lml[3][0]));
  float w0 = expf(lml[0][0] - M), w1 = expf(lml[1][0] - M);
  float w2 = expf(lml[2][0] - M), w3 = expf(lml[3][0] - M);
  float L = w0 * lml[0][1] + w1 * lml[1][1] + w2 * lml[2][1] + w3 * lml[3][1];
  int p = b * 16 + split;
  for (int h = tid; h < 1024; h += 256)
    facc[(size_t)p * 1024 + h] =
        w0 * lacc[0][h] + w1 * lacc[1][h] + w2 * lacc[2][h] + w3 * lacc[3][h];
  if (tid == 0) { fm[p] = M; fl[p] = L; }
}

// ---------------- fused: flash combine + history softmax -> xT2 (256 blocks: b x quarter) ----------------
__global__ __launch_bounds__(256) void k_ctx(const float* __restrict__ enc,
                                             const float* __restrict__ fm,
                                             const float* __restrict__ fl,
                                             const float* __restrict__ facc,
                                             const float* __restrict__ kvp,
                                             const float* __restrict__ b_ko,
                                             const float* __restrict__ buf,
                                             const float* __restrict__ inpT,
                                             float* __restrict__ xT2, int tv) {
  __shared__ float pw[TT];
  int b = blockIdx.x >> 2, qd = blockIdx.x & 3;
  int tid = threadIdx.x;
  if (tid < tv) {
    float s = b_ko[0];
    for (int g = 0; g < 64; ++g) s += kvp[((size_t)g * TT + tid) * 64 + b];  // ordered
    pw[tid] = s;
  }
  __syncthreads();
  float mx = -1e30f;
  for (int k = 0; k < tv; ++k) mx = fmaxf(mx, pw[k]);
  float den = 0.f;
  for (int k = 0; k < tv; ++k) den += expf(pw[k] - mx);
  float invd = 1.f / den;
  __syncthreads();
  if (tid < tv) pw[tid] = expf(pw[tid] - mx) * invd;
  __syncthreads();
  float M = -1e30f;
#pragma unroll
  for (int k = 0; k < 16; ++k) M = fmaxf(M, fm[b * 16 + k]);
  float w[16];
  float L = 0.f;
#pragma unroll
  for (int k = 0; k < 16; ++k) {
    w[k] = expf(fm[b * 16 + k] - M);
    L += w[k] * fl[b * 16 + k];
  }
  float inv = 1.f / L;
  {
    int h = qd * 256 + tid;
    float s = 0.f;
#pragma unroll
    for (int k = 0; k < 16; ++k) s += w[k] * facc[(size_t)(b * 16 + k) * 1024 + h];
    xT2[h * 64 + b] = enc[(size_t)b * SE * HD + h] + s * inv;  // sent = enc[:,0,:]
  }
  if (tid < 128) {
    int e = qd * 128 + tid;
    float a = 0.f;
    for (int k = 0; k < tv; ++k) a += pw[k] * buf[((size_t)b * TT + k) * 512 + e];
    xT2[(1024 + e) * 64 + b] = inpT[e * 64 + b] + a;
  }
}

// ---------------- fused h1 GEMM: intra-block split-K + bias+relu -> h1T ----------------
__global__ __launch_bounds__(256) void k_h12(const float* __restrict__ xT2,
                                             const float* __restrict__ w_m1,
                                             const float* __restrict__ b_m1,
                                             float* __restrict__ h1T) {
  __shared__ float wl[8 * 1536];  // 48 KB
  int tid = threadIdx.x;
  int r0 = blockIdx.x * 8;
  for (int i = tid; i < 3072; i += 256) {
    int lr = i / 384, kq = i % 384;
    *(float4*)&wl[lr * 1536 + kq * 4] = *(const float4*)&w_m1[(size_t)(r0 + lr) * MM + kq * 4];
  }
  __syncthreads();
  int lane = tid & 63, wid = tid >> 6;
  int kbase = wid * 384;
  const float* xp = xT2 + (size_t)kbase * 64 + lane;
  float acc[8] = {0, 0, 0, 0, 0, 0, 0, 0};
#pragma unroll 2
  for (int k4 = 0; k4 < 96; ++k4) {
    float x0 = xp[(4 * k4 + 0) * 64];
    float x1 = xp[(4 * k4 + 1) * 64];
    float x2 = xp[(4 * k4 + 2) * 64];
    float x3 = xp[(4 * k4 + 3) * 64];
#pragma unroll
    for (int lr = 0; lr < 8; ++lr) {
      const float4 w4 = *(const float4*)&wl[lr * 1536 + kbase + 4 * k4];
      acc[lr] = fmaf(w4.x, x0, acc[lr]);
      acc[lr] = fmaf(w4.y, x1, acc[lr]);
      acc[lr] = fmaf(w4.z, x2, acc[lr]);
      acc[lr] = fmaf(w4.w, x3, acc[lr]);
    }
  }
  __syncthreads();
#pragma unroll
  for (int lr = 0; lr < 8; ++lr) wl[wid * 512 + lr * 64 + lane] = acc[lr];
  __syncthreads();
  for (int e = tid; e < 512; e += 256) {
    int lr = e >> 6, b = e & 63;
    float v = b_m1[r0 + lr];
#pragma unroll
    for (int w = 0; w < 4; ++w) v += wl[w * 512 + lr * 64 + b];
    h1T[(size_t)(r0 + lr) * 64 + b] = fmaxf(v, 0.f);
  }
}

// ---------------- fused vocab GEMM: intra-block split-K + bias+mask+argmax-partial+out ----------------
__global__ __launch_bounds__(256) void k_glogfin2(const float* __restrict__ h1T,
                                                  const float* __restrict__ w_m2,
                                                  const float* __restrict__ b_m2,
                                                  const float* __restrict__ maskT,
                                                  float* __restrict__ argv, int* __restrict__ argi,
                                                  float* __restrict__ out, int t) {
  __shared__ float wl[8 * 1536];  // 48 KB; reused: sacc [0,2048), logit tile [2048,2560)
  int tid = threadIdx.x;
  int r0 = blockIdx.x * 8;  // 1250 * 8 = 10000 exactly
  for (int i = tid; i < 3072; i += 256) {
    int lr = i / 384, kq = i % 384;
    *(float4*)&wl[lr * 1536 + kq * 4] = *(const float4*)&w_m2[(size_t)(r0 + lr) * MM + kq * 4];
  }
  __syncthreads();
  int lane = tid & 63, wid = tid >> 6;
  int kbase = wid * 384;
  const float* xp = h1T + (size_t)kbase * 64 + lane;
  float acc[8] = {0, 0, 0, 0, 0, 0, 0, 0};
#pragma unroll 2
  for (int k4 = 0; k4 < 96; ++k4) {
    float x0 = xp[(4 * k4 + 0) * 64];
    float x1 = xp[(4 * k4 + 1) * 64];
    float x2 = xp[(4 * k4 + 2) * 64];
    float x3 = xp[(4 * k4 + 3) * 64];
#pragma unroll
    for (int lr = 0; lr < 8; ++lr) {
      const float4 w4 = *(const float4*)&wl[lr * 1536 + kbase + 4 * k4];
      acc[lr] = fmaf(w4.x, x0, acc[lr]);
      acc[lr] = fmaf(w4.y, x1, acc[lr]);
      acc[lr] = fmaf(w4.z, x2, acc[lr]);
      acc[lr] = fmaf(w4.w, x3, acc[lr]);
    }
  }
  __syncthreads();
#pragma unroll
  for (int lr = 0; lr < 8; ++lr) wl[wid * 512 + lr * 64 + lane] = acc[lr];
  __syncthreads();
  for (int e = tid; e < 512; e += 256) {
    int lr = e >> 6, b = e & 63;
    int r = r0 + lr;
    float v = b_m2[r] + maskT[(size_t)r * 64 + b];
#pragma unroll
    for (int w = 0; w < 4; ++w) v += wl[w * 512 + lr * 64 + b];
    wl[2048 + lr * 64 + b] = v;  // disjoint from sacc region
  }
  __syncthreads();
  if (tid < 64) {
    int b = tid;
    float best = -3.4e38f;
    int bi = 0;
#pragma unroll
    for (int lr = 0; lr < 8; ++lr) {
      float v = wl[2048 + lr * 64 + b];
      if (v > best) { best = v; bi = r0 + lr; }  // strict >, ascending rows: first-max (np.argmax)
    }
    argv[(size_t)blockIdx.x * 64 + b] = best;
    argi[(size_t)blockIdx.x * 64 + b] = bi;
  }
  for (int e = tid; e < 512; e += 256) {
    int b = e >> 3, lr = e & 7;  // 8 consecutive n per b -> 32B chunks
    out[((size_t)b * TT + t) * NV + r0 + lr] = wl[2048 + lr * 64 + b];
  }
}

// ---------------- final argmax (per-batch block) + feedback ----------------
__global__ __launch_bounds__(256) void k_final(const float* __restrict__ argv,
                                               const int* __restrict__ argi,
                                               const float* __restrict__ emb,
                                               float* __restrict__ maskT,
                                               float* __restrict__ xnext,  // inp section dest
                                               float* __restrict__ buf, float* __restrict__ bufT,
                                               float* __restrict__ out_ids, int t) {
  __shared__ float sv[256];
  __shared__ int si_[256];
  __shared__ int sid;
  int b = blockIdx.x, tid = threadIdx.x;
  float best = -3.4e38f;
  int bi = 0x7fffffff;
  for (int g = tid; g < 1250; g += 256) {
    float v = argv[(size_t)g * 64 + b];
    int idx = argi[(size_t)g * 64 + b];
    if (v > best || (v == best && idx < bi)) { best = v; bi = idx; }
  }
  sv[tid] = best;
  si_[tid] = bi;
  __syncthreads();
  for (int off = 128; off; off >>= 1) {
    if (tid < off) {
      float v2 = sv[tid + off];
      int i2 = si_[tid + off];
      if (v2 > sv[tid] || (v2 == sv[tid] && i2 < si_[tid])) { sv[tid] = v2; si_[tid] = i2; }
    }
    __syncthreads();
  }
  if (tid == 0) {
    sid = si_[0];
    out_ids[b * TT + t] = (float)si_[0];
    if (si_[0] != 1) maskT[(size_t)si_[0] * 64 + b] = MASK_VALF;  // EOS(1) stays 0
  }
  __syncthreads();
  int id = sid;
  for (int e = tid; e < 512; e += 256) {
    float v = emb[(size_t)id * 512 + e];
    xnext[e * 64 + b] = v;  // inp for next step
    buf[((size_t)b * TT + t) * 512 + e] = v;
    bufT[(size_t)e * (TT * 64) + t * 64 + b] = v;
  }
}

// ---------------- incremental history score for buf column j ----------------
__global__ __launch_bounds__(256) void k_kscore(const float* __restrict__ bufT,
                                                const float* __restrict__ w_k,
                                                const float* __restrict__ b_k,
                                                const float* __restrict__ w_ko,
                                                float* __restrict__ kvp, int j) {
  __shared__ float sacc[4][8][64];
  int lane = threadIdx.x & 63, wid = threadIdx.x >> 6;
  int ug = blockIdx.x;  // 0..63
  int u0 = ug * 8;
  int k0 = wid * 128;
  const float* xp = bufT + (size_t)j * 64 + lane;
  float acc[8] = {0, 0, 0, 0, 0, 0, 0, 0};
  for (int k4 = 0; k4 < 32; ++k4) {
    int e = k0 + 4 * k4;
    float x0 = xp[(size_t)(e + 0) * (TT * 64)];
    float x1 = xp[(size_t)(e + 1) * (TT * 64)];
    float x2 = xp[(size_t)(e + 2) * (TT * 64)];
    float x3 = xp[(size_t)(e + 3) * (TT * 64)];
#pragma unroll
    for (int i = 0; i < 8; ++i) {
      const float4 w4 = *(const float4*)&w_k[(size_t)(u0 + i) * 512 + e];
      acc[i] = fmaf(w4.x, x0, acc[i]);
      acc[i] = fmaf(w4.y, x1, acc[i]);
      acc[i] = fmaf(w4.z, x2, acc[i]);
      acc[i] = fmaf(w4.w, x3, acc[i]);
    }
  }
#pragma unroll
  for (int i = 0; i < 8; ++i) sacc[wid][i][lane] = acc[i];
  __syncthreads();
  if (wid == 0) {
    float kp = 0.f;
#pragma unroll
    for (int i = 0; i < 8; ++i) {
      float tot = b_k[u0 + i] + sacc[0][i][lane] + sacc[1][i][lane] + sacc[2][i][lane] +
                  sacc[3][i][lane];
      kp += fmaxf(tot, 0.f) * w_ko[u0 + i];
    }
    kvp[((size_t)ug * TT + j) * 64 + lane] = kp;
  }
}

extern "C" void kernel_launch(void* const* d_in, const int* in_sizes, int n_in,
                              void* d_out, int out_size, void* d_ws, size_t ws_size,
                              hipStream_t stream) {
  const float* enc = (const float*)d_in[0];
  const float* h0 = (const float*)d_in[1];
  const float* c0 = (const float*)d_in[2];
  const int* tlen = (const int*)d_in[3];
  const float* emb = (const float*)d_in[5];
  const float* w_ih = (const float*)d_in[6];
  const float* w_hh = (const float*)d_in[7];
  const float* b_ih = (const float*)d_in[8];
  const float* b_hh = (const float*)d_in[9];
  const float* w_q = (const float*)d_in[10];
  const float* b_q = (const float*)d_in[11];
  const float* w_k = (const float*)d_in[12];
  const float* b_k = (const float*)d_in[13];
  const float* w_ko = (const float*)d_in[14];
  const float* b_ko = (const float*)d_in[15];
  const float* w_m1 = (const float*)d_in[16];
  const float* b_m1 = (const float*)d_in[17];
  const float* w_m2 = (const float*)d_in[18];
  const float* b_m2 = (const float*)d_in[19];

  float* ws = (float*)d_ws;
  float* out_logits = (float*)d_out;
  float* out_ids = out_logits + (size_t)B64 * TT * NV;

  k_init<<<2048, 256, 0, stream>>>(h0, c0, ws);
  k_kscore<<<64, 256, 0, stream>>>(ws + OFF_BUFT, w_k, b_k, w_ko, ws + OFF_KVP, 0);

  for (int t = 0; t < TT; ++t) {
    int tv = (t < 1) ? 1 : t;
    float* xcur = ws + ((t & 1) ? OFF_XB : OFF_XA);
    float* xnext = ws + ((t & 1) ? OFF_XA : OFF_XB);
    k_cell<<<512, 256, 0, stream>>>(xcur, w_ih, w_hh, b_ih, b_hh, ws + OFF_CT, xnext);
    k_q2<<<128, 256, 0, stream>>>(xnext + 512 * 64, w_q, b_q, ws + OFF_QF);
    k_flash<<<1024, 256, 0, stream>>>(enc, tlen, ws + OFF_QF, ws + OFF_FM, ws + OFF_FL,
                                      ws + OFF_FACC);
    k_ctx<<<256, 256, 0, stream>>>(enc, ws + OFF_FM, ws + OFF_FL, ws + OFF_FACC, ws + OFF_KVP,
                                   b_ko, ws + OFF_BUF, xcur, ws + OFF_XT2, tv);
    k_h12<<<192, 256, 0, stream>>>(ws + OFF_XT2, w_m1, b_m1, ws + OFF_H1T);
    k_glogfin2<<<1250, 256, 0, stream>>>(ws + OFF_H1T, w_m2, b_m2, ws + OFF_MASKT, ws + OFF_ARGV,
                                         (int*)(ws + OFF_ARGI), out_logits, t);
    k_final<<<64, 256, 0, stream>>>(ws + OFF_ARGV, (int*)(ws + OFF_ARGI), emb, ws + OFF_MASKT,
                                    xnext, ws + OFF_BUF, ws + OFF_BUFT, out_ids, t);
    if (t < TT - 1)
      k_kscore<<<64, 256, 0, stream>>>(ws + OFF_BUFT, w_k, b_k, w_ko, ws + OFF_KVP, t);
  }
}

// Round 9
// 3178.032 us; speedup vs baseline: 3.2787x; 1.0985x over previous
//
#include <hip/hip_runtime.h>

#define B64 64
#define SE 512
#define HD 1024
#define ED 512
#define NV 10000
#define TT 20
#define MM 1536
#define MASK_VALF -10000000.0f

// ---- workspace offsets (floats) ----
#define OFF_XA    0          // [inp(512) | h(1024)] x 64, parity A
#define OFF_XB    98304      // parity B
#define OFF_CT    196608     // cT [1024][64]
#define OFF_QF    262144     // qf [64][1024]
#define OFF_FM    327680     // [1024]
#define OFF_FL    328704     // [1024]
#define OFF_FACC  329728     // [1024][1024]
#define OFF_XT2   1378304    // [1536][64]
#define OFF_H1T   1476608    // [1536][64]
#define OFF_ARGV  1574912    // [1250][64]
#define OFF_ARGI  1654912    // [1250][64] (int)
#define OFF_MASKT 1734912    // [10000][64]
#define OFF_BUF   2374912    // [64][20][512]
#define OFF_BUFT  3030272    // [512][20][64]
#define OFF_KVP   3685632    // [64][20][64]
#define OFF_LP    3767552    // [6][10000][64] vocab partials
// end: 7607552 floats ~= 30.4 MB

__device__ __forceinline__ float sigmoidf_(float x) { return 1.f / (1.f + expf(-x)); }

// ---------------- init ----------------
__global__ __launch_bounds__(256) void k_init(const float* __restrict__ h0,
                                              const float* __restrict__ c0,
                                              float* __restrict__ ws) {
  int idx = blockIdx.x * 256 + threadIdx.x, stride = gridDim.x * 256;
  float* xa = ws + OFF_XA;
  float* cT = ws + OFF_CT;
  float* maskT = ws + OFF_MASKT;
  float* buf = ws + OFF_BUF;
  float* bufT = ws + OFF_BUFT;
  for (int i = idx; i < 512 * 64; i += stride) xa[i] = 0.f;  // inp section
  for (int i = idx; i < NV * 64; i += stride) maskT[i] = 0.f;
  for (int i = idx; i < B64 * TT * ED; i += stride) { buf[i] = 0.f; bufT[i] = 0.f; }
  for (int i = idx; i < HD * 64; i += stride) {
    int u = i >> 6, b = i & 63;
    xa[512 * 64 + i] = h0[b * HD + u];  // h section
    cT[i] = c0[b * HD + u];
  }
}

// ---------------- fused LSTM cell: intra-block split-K (4 waves x K/4) + pointwise ----------------
__global__ __launch_bounds__(256) void k_cell(const float* __restrict__ xcur,
                                              const float* __restrict__ w_ih,
                                              const float* __restrict__ w_hh,
                                              const float* __restrict__ b_ih,
                                              const float* __restrict__ b_hh,
                                              float* __restrict__ cT,
                                              float* __restrict__ xnext) {
  __shared__ float wl[8 * 1536];  // 48 KB; reused for cross-wave reduce
  int tid = threadIdx.x;
  int u0 = blockIdx.x * 2;
  for (int i = tid; i < 3072; i += 256) {
    int lr = i / 384, kq = i % 384;
    int k = kq * 4;
    int grow = (lr >> 1) * 1024 + u0 + (lr & 1);
    float4 v;
    if (k < 512) v = *(const float4*)&w_ih[(size_t)grow * 512 + k];
    else v = *(const float4*)&w_hh[(size_t)grow * 1024 + (k - 512)];
    *(float4*)&wl[lr * 1536 + k] = v;
  }
  __syncthreads();
  int lane = tid & 63, wid = tid >> 6;
  int kbase = wid * 384;
  const float* xp = xcur + (size_t)kbase * 64 + lane;
  float acc[8] = {0, 0, 0, 0, 0, 0, 0, 0};
#pragma unroll 2
  for (int k4 = 0; k4 < 96; ++k4) {
    float x0 = xp[(4 * k4 + 0) * 64];
    float x1 = xp[(4 * k4 + 1) * 64];
    float x2 = xp[(4 * k4 + 2) * 64];
    float x3 = xp[(4 * k4 + 3) * 64];
#pragma unroll
    for (int lr = 0; lr < 8; ++lr) {
      const float4 w4 = *(const float4*)&wl[lr * 1536 + kbase + 4 * k4];
      acc[lr] = fmaf(w4.x, x0, acc[lr]);
      acc[lr] = fmaf(w4.y, x1, acc[lr]);
      acc[lr] = fmaf(w4.z, x2, acc[lr]);
      acc[lr] = fmaf(w4.w, x3, acc[lr]);
    }
  }
  __syncthreads();  // weights dead; reuse wl for reduce
#pragma unroll
  for (int lr = 0; lr < 8; ++lr) wl[wid * 512 + lr * 64 + lane] = acc[lr];
  __syncthreads();
  if (tid < 128) {
    int j = tid >> 6, b = tid & 63;
    float g4[4];
#pragma unroll
    for (int g = 0; g < 4; ++g) {
      int lr = g * 2 + j;
      int grow = g * 1024 + u0 + j;
      float v = b_ih[grow] + b_hh[grow];
#pragma unroll
      for (int w = 0; w < 4; ++w) v += wl[w * 512 + lr * 64 + b];  // fixed order: deterministic
      g4[g] = v;
    }
    int u = u0 + j;
    float c = cT[u * 64 + b];
    float cn = sigmoidf_(g4[1]) * c + sigmoidf_(g4[0]) * tanhf(g4[2]);
    float hn = sigmoidf_(g4[3]) * tanhf(cn);
    cT[u * 64 + b] = cn;
    xnext[(512 + u) * 64 + b] = hn;
  }
}

// ---------------- fused q GEMM: intra-block split-K + combine -> qf[b][h] ----------------
__global__ __launch_bounds__(256) void k_q2(const float* __restrict__ h,
                                            const float* __restrict__ w_q,
                                            const float* __restrict__ b_q,
                                            float* __restrict__ qf) {
  __shared__ float wl[8 * 1024];  // 32 KB
  int tid = threadIdx.x;
  int h0 = blockIdx.x * 8;
  for (int i = tid; i < 2048; i += 256) {
    int lr = i >> 8, kq = i & 255;
    *(float4*)&wl[lr * 1024 + kq * 4] = *(const float4*)&w_q[(size_t)(h0 + lr) * 1024 + kq * 4];
  }
  __syncthreads();
  int lane = tid & 63, wid = tid >> 6;
  int kbase = wid * 256;
  const float* xp = h + (size_t)kbase * 64 + lane;
  float acc[8] = {0, 0, 0, 0, 0, 0, 0, 0};
#pragma unroll 2
  for (int k4 = 0; k4 < 64; ++k4) {
    float x0 = xp[(4 * k4 + 0) * 64];
    float x1 = xp[(4 * k4 + 1) * 64];
    float x2 = xp[(4 * k4 + 2) * 64];
    float x3 = xp[(4 * k4 + 3) * 64];
#pragma unroll
    for (int lr = 0; lr < 8; ++lr) {
      const float4 w4 = *(const float4*)&wl[lr * 1024 + kbase + 4 * k4];
      acc[lr] = fmaf(w4.x, x0, acc[lr]);
      acc[lr] = fmaf(w4.y, x1, acc[lr]);
      acc[lr] = fmaf(w4.z, x2, acc[lr]);
      acc[lr] = fmaf(w4.w, x3, acc[lr]);
    }
  }
  __syncthreads();
#pragma unroll
  for (int lr = 0; lr < 8; ++lr) wl[wid * 512 + lr * 64 + lane] = acc[lr];
  __syncthreads();
  for (int e = tid; e < 512; e += 256) {
    int lr = e >> 6, b = e & 63;
    float v = b_q[h0 + lr];
#pragma unroll
    for (int w = 0; w < 4; ++w) v += wl[w * 512 + lr * 64 + b];
    qf[(size_t)b * 1024 + h0 + lr] = v;
  }
}

// ---------------- flash attention: 16 s-splits, 8 rows/wave, pair-pipelined (R4-proven) ----------------
__global__ __launch_bounds__(256) void k_flash(const float* __restrict__ enc,
                                               const int* __restrict__ tlen,
                                               const float* __restrict__ qf,
                                               float* __restrict__ fm, float* __restrict__ fl,
                                               float* __restrict__ facc) {
  __shared__ float lacc[4][1024];
  __shared__ float lml[4][2];
  int b = blockIdx.x >> 4, split = blockIdx.x & 15;
  int tid = threadIdx.x, lane = tid & 63, wid = tid >> 6;
  int len = tlen[b];
  float qv[16];
#pragma unroll
  for (int j = 0; j < 4; ++j) {
    float4 tq = *(const float4*)&qf[(size_t)b * 1024 + j * 256 + lane * 4];
    qv[4 * j + 0] = tq.x; qv[4 * j + 1] = tq.y; qv[4 * j + 2] = tq.z; qv[4 * j + 3] = tq.w;
  }
  const float* base = enc + (size_t)b * SE * HD;
  int s0 = split * 32 + wid * 8;
  int nr = len - s0;
  nr = nr < 0 ? 0 : (nr > 8 ? 8 : nr);
  int npair = nr >> 1;

  float4 cA[4], cB[4], nA[4], nB[4];
  float m = -1e30f, l = 0.f, acc[16];
#pragma unroll
  for (int j = 0; j < 16; ++j) acc[j] = 0.f;

#define LOADROW(d, s)                                                 \
  {                                                                   \
    const float4* rp = (const float4*)(base + (size_t)(s)*HD) + lane; \
    d[0] = rp[0]; d[1] = rp[64]; d[2] = rp[128]; d[3] = rp[192];      \
  }

  if (npair > 0) { LOADROW(cA, s0); LOADROW(cB, s0 + 1); }
  for (int p = 0; p < npair; ++p) {
    if (p + 1 < npair) {
      LOADROW(nA, s0 + 2 * p + 2);
      LOADROW(nB, s0 + 2 * p + 3);
    } else if (nr & 1) {
      LOADROW(nA, s0 + nr - 1);
    }
    float d0 = 0.f, d1 = 0.f;
#pragma unroll
    for (int j = 0; j < 4; ++j) {
      d0 = fmaf(qv[4 * j + 0], cA[j].x, d0); d1 = fmaf(qv[4 * j + 0], cB[j].x, d1);
      d0 = fmaf(qv[4 * j + 1], cA[j].y, d0); d1 = fmaf(qv[4 * j + 1], cB[j].y, d1);
      d0 = fmaf(qv[4 * j + 2], cA[j].z, d0); d1 = fmaf(qv[4 * j + 2], cB[j].z, d1);
      d0 = fmaf(qv[4 * j + 3], cA[j].w, d0); d1 = fmaf(qv[4 * j + 3], cB[j].w, d1);
    }
#pragma unroll
    for (int off = 32; off; off >>= 1) { d0 += __shfl_xor(d0, off, 64); d1 += __shfl_xor(d1, off, 64); }
    d0 = __shfl(d0, 0, 64);
    d1 = __shfl(d1, 0, 64);
    float mn = fmaxf(m, fmaxf(d0, d1));
    float sc = expf(m - mn), p0 = expf(d0 - mn), p1 = expf(d1 - mn);
    l = l * sc + p0 + p1;
#pragma unroll
    for (int j = 0; j < 4; ++j) {
      acc[4 * j + 0] = fmaf(p1, cB[j].x, fmaf(p0, cA[j].x, acc[4 * j + 0] * sc));
      acc[4 * j + 1] = fmaf(p1, cB[j].y, fmaf(p0, cA[j].y, acc[4 * j + 1] * sc));
      acc[4 * j + 2] = fmaf(p1, cB[j].z, fmaf(p0, cA[j].z, acc[4 * j + 2] * sc));
      acc[4 * j + 3] = fmaf(p1, cB[j].w, fmaf(p0, cA[j].w, acc[4 * j + 3] * sc));
    }
    m = mn;
#pragma unroll
    for (int j = 0; j < 4; ++j) { cA[j] = nA[j]; cB[j] = nB[j]; }
  }
  if (nr & 1) {
    if (npair == 0) LOADROW(cA, s0);
    float d0 = 0.f;
#pragma unroll
    for (int j = 0; j < 4; ++j) {
      d0 = fmaf(qv[4 * j + 0], cA[j].x, d0);
      d0 = fmaf(qv[4 * j + 1], cA[j].y, d0);
      d0 = fmaf(qv[4 * j + 2], cA[j].z, d0);
      d0 = fmaf(qv[4 * j + 3], cA[j].w, d0);
    }
#pragma unroll
    for (int off = 32; off; off >>= 1) d0 += __shfl_xor(d0, off, 64);
    d0 = __shfl(d0, 0, 64);
    float mn = fmaxf(m, d0);
    float sc = expf(m - mn), p0 = expf(d0 - mn);
    l = l * sc + p0;
#pragma unroll
    for (int j = 0; j < 4; ++j) {
      acc[4 * j + 0] = fmaf(p0, cA[j].x, acc[4 * j + 0] * sc);
      acc[4 * j + 1] = fmaf(p0, cA[j].y, acc[4 * j + 1] * sc);
      acc[4 * j + 2] = fmaf(p0, cA[j].z, acc[4 * j + 2] * sc);
      acc[4 * j + 3] = fmaf(p0, cA[j].w, acc[4 * j + 3] * sc);
    }
    m = mn;
  }
#undef LOADROW
#pragma unroll
  for (int j = 0; j < 4; ++j)
    *(float4*)&lacc[wid][j * 256 + lane * 4] =
        make_float4(acc[4 * j], acc[4 * j + 1], acc[4 * j + 2], acc[4 * j + 3]);
  if (lane == 0) { lml[wid][0] = m; lml[wid][1] = l; }
  __syncthreads();
  float M = fmaxf(fmaxf(lml[0][0], lml[1][0]), fmaxf(lml[2][0], lml[3][0]));
  float w0 = expf(lml[0][0] - M), w1 = expf(lml[1][0] - M);
  float w2 = expf(lml[2][0] - M), w3 = expf(lml[3][0] - M);
  float L = w0 * lml[0][1] + w1 * lml[1][1] + w2 * lml[2][1] + w3 * lml[3][1];
  int p = b * 16 + split;
  for (int h = tid; h < 1024; h += 256)
    facc[(size_t)p * 1024 + h] =
        w0 * lacc[0][h] + w1 * lacc[1][h] + w2 * lacc[2][h] + w3 * lacc[3][h];
  if (tid == 0) { fm[p] = M; fl[p] = L; }
}

// ---------------- fused: flash combine + history softmax -> xT2 (256 blocks: b x quarter) ----------------
__global__ __launch_bounds__(256) void k_ctx(const float* __restrict__ enc,
                                             const float* __restrict__ fm,
                                             const float* __restrict__ fl,
                                             const float* __restrict__ facc,
                                             const float* __restrict__ kvp,
                                             const float* __restrict__ b_ko,
                                             const float* __restrict__ buf,
                                             const float* __restrict__ inpT,
                                             float* __restrict__ xT2, int tv) {
  __shared__ float pw[TT];
  int b = blockIdx.x >> 2, qd = blockIdx.x & 3;
  int tid = threadIdx.x;
  if (tid < tv) {
    float s = b_ko[0];
    for (int g = 0; g < 64; ++g) s += kvp[((size_t)g * TT + tid) * 64 + b];  // ordered
    pw[tid] = s;
  }
  __syncthreads();
  float mx = -1e30f;
  for (int k = 0; k < tv; ++k) mx = fmaxf(mx, pw[k]);
  float den = 0.f;
  for (int k = 0; k < tv; ++k) den += expf(pw[k] - mx);
  float invd = 1.f / den;
  __syncthreads();
  if (tid < tv) pw[tid] = expf(pw[tid] - mx) * invd;
  __syncthreads();
  float M = -1e30f;
#pragma unroll
  for (int k = 0; k < 16; ++k) M = fmaxf(M, fm[b * 16 + k]);
  float w[16];
  float L = 0.f;
#pragma unroll
  for (int k = 0; k < 16; ++k) {
    w[k] = expf(fm[b * 16 + k] - M);
    L += w[k] * fl[b * 16 + k];
  }
  float inv = 1.f / L;
  {
    int h = qd * 256 + tid;
    float s = 0.f;
#pragma unroll
    for (int k = 0; k < 16; ++k) s += w[k] * facc[(size_t)(b * 16 + k) * 1024 + h];
    xT2[h * 64 + b] = enc[(size_t)b * SE * HD + h] + s * inv;  // sent = enc[:,0,:]
  }
  if (tid < 128) {
    int e = qd * 128 + tid;
    float a = 0.f;
    for (int k = 0; k < tv; ++k) a += pw[k] * buf[((size_t)b * TT + k) * 512 + e];
    xT2[(1024 + e) * 64 + b] = inpT[e * 64 + b] + a;
  }
}

// ---------------- fused h1 GEMM: intra-block split-K + bias+relu -> h1T ----------------
__global__ __launch_bounds__(256) void k_h12(const float* __restrict__ xT2,
                                             const float* __restrict__ w_m1,
                                             const float* __restrict__ b_m1,
                                             float* __restrict__ h1T) {
  __shared__ float wl[8 * 1536];  // 48 KB
  int tid = threadIdx.x;
  int r0 = blockIdx.x * 8;
  for (int i = tid; i < 3072; i += 256) {
    int lr = i / 384, kq = i % 384;
    *(float4*)&wl[lr * 1536 + kq * 4] = *(const float4*)&w_m1[(size_t)(r0 + lr) * MM + kq * 4];
  }
  __syncthreads();
  int lane = tid & 63, wid = tid >> 6;
  int kbase = wid * 384;
  const float* xp = xT2 + (size_t)kbase * 64 + lane;
  float acc[8] = {0, 0, 0, 0, 0, 0, 0, 0};
#pragma unroll 2
  for (int k4 = 0; k4 < 96; ++k4) {
    float x0 = xp[(4 * k4 + 0) * 64];
    float x1 = xp[(4 * k4 + 1) * 64];
    float x2 = xp[(4 * k4 + 2) * 64];
    float x3 = xp[(4 * k4 + 3) * 64];
#pragma unroll
    for (int lr = 0; lr < 8; ++lr) {
      const float4 w4 = *(const float4*)&wl[lr * 1536 + kbase + 4 * k4];
      acc[lr] = fmaf(w4.x, x0, acc[lr]);
      acc[lr] = fmaf(w4.y, x1, acc[lr]);
      acc[lr] = fmaf(w4.z, x2, acc[lr]);
      acc[lr] = fmaf(w4.w, x3, acc[lr]);
    }
  }
  __syncthreads();
#pragma unroll
  for (int lr = 0; lr < 8; ++lr) wl[wid * 512 + lr * 64 + lane] = acc[lr];
  __syncthreads();
  for (int e = tid; e < 512; e += 256) {
    int lr = e >> 6, b = e & 63;
    float v = b_m1[r0 + lr];
#pragma unroll
    for (int w = 0; w < 4; ++w) v += wl[w * 512 + lr * 64 + b];
    h1T[(size_t)(r0 + lr) * 64 + b] = fmaxf(v, 0.f);
  }
}

// ---------------- vocab GEMM: classic register tiling, partials lp[split][r][b] ----------------
// BM=128, BN=64, Ksplit 6x256, inner BK=32. Thread tile 8 rows x 4 batches.
__global__ __launch_bounds__(256) void k_vocab(const float* __restrict__ h1T,
                                               const float* __restrict__ w_m2,
                                               float* __restrict__ lp) {
  __shared__ float Wl[128 * 36];  // [row][36] (BK=32 + pad 4) -> 18 KB, f4-aligned
  __shared__ float Xl[32 * 68];   // [k][68]  (64 + pad 4)     -> 8.5 KB, f4-aligned
  int tid = threadIdx.x;
  int r0b = blockIdx.x * 128;  // 0..78
  int k0 = blockIdx.y * 256;   // 0..5
  int tc = tid & 15, tr = tid >> 4;
  int r0 = tr * 8, b0 = tc * 4;
  float4 acc[8];
#pragma unroll
  for (int i = 0; i < 8; ++i) acc[i] = make_float4(0.f, 0.f, 0.f, 0.f);
  for (int kt = 0; kt < 8; ++kt) {
    int kbase = k0 + kt * 32;
    // stage W tile: 128 rows x 32 k (1024 float4)
#pragma unroll
    for (int j = 0; j < 4; ++j) {
      int f = tid + 256 * j;
      int row = f >> 3, kkq = (f & 7) * 4;
      int gr = r0b + row;
      if (gr > NV - 1) gr = NV - 1;
      *(float4*)&Wl[row * 36 + kkq] = *(const float4*)&w_m2[(size_t)gr * MM + kbase + kkq];
    }
    // stage X tile: 32 k x 64 b (512 float4), straight copy (h1T is k-major)
#pragma unroll
    for (int j = 0; j < 2; ++j) {
      int f = tid + 256 * j;
      int kk = f >> 4, bq = (f & 15) * 4;
      *(float4*)&Xl[kk * 68 + bq] = *(const float4*)&h1T[(size_t)(kbase + kk) * 64 + bq];
    }
    __syncthreads();
#pragma unroll 2
    for (int kq = 0; kq < 8; ++kq) {
      float4 xv0 = *(const float4*)&Xl[(kq * 4 + 0) * 68 + b0];
      float4 xv1 = *(const float4*)&Xl[(kq * 4 + 1) * 68 + b0];
      float4 xv2 = *(const float4*)&Xl[(kq * 4 + 2) * 68 + b0];
      float4 xv3 = *(const float4*)&Xl[(kq * 4 + 3) * 68 + b0];
#pragma unroll
      for (int i = 0; i < 8; ++i) {
        float4 av = *(const float4*)&Wl[(r0 + i) * 36 + kq * 4];
        acc[i].x = fmaf(av.x, xv0.x, acc[i].x);
        acc[i].y = fmaf(av.x, xv0.y, acc[i].y);
        acc[i].z = fmaf(av.x, xv0.z, acc[i].z);
        acc[i].w = fmaf(av.x, xv0.w, acc[i].w);
        acc[i].x = fmaf(av.y, xv1.x, acc[i].x);
        acc[i].y = fmaf(av.y, xv1.y, acc[i].y);
        acc[i].z = fmaf(av.y, xv1.z, acc[i].z);
        acc[i].w = fmaf(av.y, xv1.w, acc[i].w);
        acc[i].x = fmaf(av.z, xv2.x, acc[i].x);
        acc[i].y = fmaf(av.z, xv2.y, acc[i].y);
        acc[i].z = fmaf(av.z, xv2.z, acc[i].z);
        acc[i].w = fmaf(av.z, xv2.w, acc[i].w);
        acc[i].x = fmaf(av.w, xv3.x, acc[i].x);
        acc[i].y = fmaf(av.w, xv3.y, acc[i].y);
        acc[i].z = fmaf(av.w, xv3.z, acc[i].z);
        acc[i].w = fmaf(av.w, xv3.w, acc[i].w);
      }
    }
    __syncthreads();
  }
  float* o = lp + (size_t)blockIdx.y * 640000;
#pragma unroll
  for (int i = 0; i < 8; ++i) {
    int r = r0b + r0 + i;
    if (r < NV) *(float4*)&o[(size_t)r * 64 + b0] = acc[i];
  }
}

// ---------------- logits finish: combine 6 + bias + mask + argmax partial + transposed out ----------------
__global__ __launch_bounds__(256) void k_logfin(const float* __restrict__ lp,
                                                const float* __restrict__ b_m2,
                                                const float* __restrict__ maskT,
                                                float* __restrict__ argv, int* __restrict__ argi,
                                                float* __restrict__ out, int t) {
  __shared__ float tile[32][65];
  int lane = threadIdx.x & 63, wid = threadIdx.x >> 6;
  int rg = blockIdx.x * 4 + wid;
  int nb = blockIdx.x * 32;
  if (rg < 1250) {
    int r0 = rg * 8;
    float best = -3.4e38f;
    int bi = 0;
#pragma unroll
    for (int i = 0; i < 8; ++i) {
      int r = r0 + i;
      size_t idx = (size_t)r * 64 + lane;
      float v = b_m2[r] + maskT[idx];
#pragma unroll
      for (int s = 0; s < 6; ++s) v += lp[(size_t)s * 640000 + idx];
      tile[wid * 8 + i][lane] = v;
      if (v > best) { best = v; bi = r; }  // strict >: first-max (np.argmax)
    }
    argv[(size_t)rg * 64 + lane] = best;
    argi[(size_t)rg * 64 + lane] = bi;
  }
  __syncthreads();
  int b = threadIdx.x >> 2, q = threadIdx.x & 3;
  int nloc = q * 8;
  if (nb + nloc < NV) {
    float tmp[8];
#pragma unroll
    for (int c = 0; c < 8; ++c) tmp[c] = tile[nloc + c][b];
    float4* o = (float4*)&out[((size_t)b * TT + t) * NV + nb + nloc];
    o[0] = make_float4(tmp[0], tmp[1], tmp[2], tmp[3]);
    o[1] = make_float4(tmp[4], tmp[5], tmp[6], tmp[7]);
  }
}

// ---------------- final argmax (per-batch block) + feedback ----------------
__global__ __launch_bounds__(256) void k_final(const float* __restrict__ argv,
                                               const int* __restrict__ argi,
                                               const float* __restrict__ emb,
                                               float* __restrict__ maskT,
                                               float* __restrict__ xnext,  // inp section dest
                                               float* __restrict__ buf, float* __restrict__ bufT,
                                               float* __restrict__ out_ids, int t) {
  __shared__ float sv[256];
  __shared__ int si_[256];
  __shared__ int sid;
  int b = blockIdx.x, tid = threadIdx.x;
  float best = -3.4e38f;
  int bi = 0x7fffffff;
  for (int g = tid; g < 1250; g += 256) {
    float v = argv[(size_t)g * 64 + b];
    int idx = argi[(size_t)g * 64 + b];
    if (v > best || (v == best && idx < bi)) { best = v; bi = idx; }
  }
  sv[tid] = best;
  si_[tid] = bi;
  __syncthreads();
  for (int off = 128; off; off >>= 1) {
    if (tid < off) {
      float v2 = sv[tid + off];
      int i2 = si_[tid + off];
      if (v2 > sv[tid] || (v2 == sv[tid] && i2 < si_[tid])) { sv[tid] = v2; si_[tid] = i2; }
    }
    __syncthreads();
  }
  if (tid == 0) {
    sid = si_[0];
    out_ids[b * TT + t] = (float)si_[0];
    if (si_[0] != 1) maskT[(size_t)si_[0] * 64 + b] = MASK_VALF;  // EOS(1) stays 0
  }
  __syncthreads();
  int id = sid;
  for (int e = tid; e < 512; e += 256) {
    float v = emb[(size_t)id * 512 + e];
    xnext[e * 64 + b] = v;  // inp for next step
    buf[((size_t)b * TT + t) * 512 + e] = v;
    bufT[(size_t)e * (TT * 64) + t * 64 + b] = v;
  }
}

// ---------------- incremental history score for buf column j ----------------
__global__ __launch_bounds__(256) void k_kscore(const float* __restrict__ bufT,
                                                const float* __restrict__ w_k,
                                                const float* __restrict__ b_k,
                                                const float* __restrict__ w_ko,
                                                float* __restrict__ kvp, int j) {
  __shared__ float sacc[4][8][64];
  int lane = threadIdx.x & 63, wid = threadIdx.x >> 6;
  int ug = blockIdx.x;  // 0..63
  int u0 = ug * 8;
  int k0 = wid * 128;
  const float* xp = bufT + (size_t)j * 64 + lane;
  float acc[8] = {0, 0, 0, 0, 0, 0, 0, 0};
  for (int k4 = 0; k4 < 32; ++k4) {
    int e = k0 + 4 * k4;
    float x0 = xp[(size_t)(e + 0) * (TT * 64)];
    float x1 = xp[(size_t)(e + 1) * (TT * 64)];
    float x2 = xp[(size_t)(e + 2) * (TT * 64)];
    float x3 = xp[(size_t)(e + 3) * (TT * 64)];
#pragma unroll
    for (int i = 0; i < 8; ++i) {
      const float4 w4 = *(const float4*)&w_k[(size_t)(u0 + i) * 512 + e];
      acc[i] = fmaf(w4.x, x0, acc[i]);
      acc[i] = fmaf(w4.y, x1, acc[i]);
      acc[i] = fmaf(w4.z, x2, acc[i]);
      acc[i] = fmaf(w4.w, x3, acc[i]);
    }
  }
#pragma unroll
  for (int i = 0; i < 8; ++i) sacc[wid][i][lane] = acc[i];
  __syncthreads();
  if (wid == 0) {
    float kp = 0.f;
#pragma unroll
    for (int i = 0; i < 8; ++i) {
      float tot = b_k[u0 + i] + sacc[0][i][lane] + sacc[1][i][lane] + sacc[2][i][lane] +
                  sacc[3][i][lane];
      kp += fmaxf(tot, 0.f) * w_ko[u0 + i];
    }
    kvp[((size_t)ug * TT + j) * 64 + lane] = kp;
  }
}

extern "C" void kernel_launch(void* const* d_in, const int* in_sizes, int n_in,
                              void* d_out, int out_size, void* d_ws, size_t ws_size,
                              hipStream_t stream) {
  const float* enc = (const float*)d_in[0];
  const float* h0 = (const float*)d_in[1];
  const float* c0 = (const float*)d_in[2];
  const int* tlen = (const int*)d_in[3];
  const float* emb = (const float*)d_in[5];
  const float* w_ih = (const float*)d_in[6];
  const float* w_hh = (const float*)d_in[7];
  const float* b_ih = (const float*)d_in[8];
  const float* b_hh = (const float*)d_in[9];
  const float* w_q = (const float*)d_in[10];
  const float* b_q = (const float*)d_in[11];
  const float* w_k = (const float*)d_in[12];
  const float* b_k = (const float*)d_in[13];
  const float* w_ko = (const float*)d_in[14];
  const float* b_ko = (const float*)d_in[15];
  const float* w_m1 = (const float*)d_in[16];
  const float* b_m1 = (const float*)d_in[17];
  const float* w_m2 = (const float*)d_in[18];
  const float* b_m2 = (const float*)d_in[19];

  float* ws = (float*)d_ws;
  float* out_logits = (float*)d_out;
  float* out_ids = out_logits + (size_t)B64 * TT * NV;

  k_init<<<2048, 256, 0, stream>>>(h0, c0, ws);
  k_kscore<<<64, 256, 0, stream>>>(ws + OFF_BUFT, w_k, b_k, w_ko, ws + OFF_KVP, 0);

  for (int t = 0; t < TT; ++t) {
    int tv = (t < 1) ? 1 : t;
    float* xcur = ws + ((t & 1) ? OFF_XB : OFF_XA);
    float* xnext = ws + ((t & 1) ? OFF_XA : OFF_XB);
    k_cell<<<512, 256, 0, stream>>>(xcur, w_ih, w_hh, b_ih, b_hh, ws + OFF_CT, xnext);
    k_q2<<<128, 256, 0, stream>>>(xnext + 512 * 64, w_q, b_q, ws + OFF_QF);
    k_flash<<<1024, 256, 0, stream>>>(enc, tlen, ws + OFF_QF, ws + OFF_FM, ws + OFF_FL,
                                      ws + OFF_FACC);
    k_ctx<<<256, 256, 0, stream>>>(enc, ws + OFF_FM, ws + OFF_FL, ws + OFF_FACC, ws + OFF_KVP,
                                   b_ko, ws + OFF_BUF, xcur, ws + OFF_XT2, tv);
    k_h12<<<192, 256, 0, stream>>>(ws + OFF_XT2, w_m1, b_m1, ws + OFF_H1T);
    k_vocab<<<dim3(79, 6), 256, 0, stream>>>(ws + OFF_H1T, w_m2, ws + OFF_LP);
    k_logfin<<<313, 256, 0, stream>>>(ws + OFF_LP, b_m2, ws + OFF_MASKT, ws + OFF_ARGV,
                                      (int*)(ws + OFF_ARGI), out_logits, t);
    k_final<<<64, 256, 0, stream>>>(ws + OFF_ARGV, (int*)(ws + OFF_ARGI), emb, ws + OFF_MASKT,
                                    xnext, ws + OFF_BUF, ws + OFF_BUFT, out_ids, t);
    if (t < TT - 1)
      k_kscore<<<64, 256, 0, stream>>>(ws + OFF_BUFT, w_k, b_k, w_ko, ws + OFF_KVP, t);
  }
}